// Round 1
// baseline (754.244 us; speedup 1.0000x reference)
//
#include <hip/hip_runtime.h>

// GCN fused: B=16384 graphs, N=16 nodes, 256 -> 128 -> 64 -> 32, mean over nodes.
// Round 1: correctness-first fp32, one block (256 thr) per graph, all
// intermediates in LDS. mean_n(adj@s3 + b3) folded to colmean(adj)^T @ s3 + b3.

__global__ __launch_bounds__(256) void gcn_fused(
    const float* __restrict__ x,     // [B,16,256]
    const float* __restrict__ adj,   // [B,16,16]
    const float* __restrict__ W1,    // [256,128]
    const float* __restrict__ b1,    // [128]
    const float* __restrict__ W2,    // [128,64]
    const float* __restrict__ b2,    // [64]
    const float* __restrict__ W3,    // [64,32]
    const float* __restrict__ b3,    // [32]
    float* __restrict__ out)         // [B,32]
{
    constexpr int N = 16, D_IN = 256, D_H = 128, D_H2 = 64, D_OUT = 32;
    __shared__ float s_x[N][D_IN];    // 16 KB input tile
    __shared__ float s_adj[N][N];     // 1 KB
    __shared__ float s_a[N][D_H];     // 8 KB ping
    __shared__ float s_b_[N][D_H];    // 8 KB pong
    __shared__ float s_c[N];          // adj column means

    const int g = blockIdx.x;
    const int t = threadIdx.x;

    // ---- stage x tile (4096 floats as float4) and adj (256 floats)
    {
        const float4* src = (const float4*)(x + (size_t)g * (N * D_IN));
        float4* dst = (float4*)&s_x[0][0];
        #pragma unroll
        for (int i = 0; i < 4; ++i) dst[t + 256 * i] = src[t + 256 * i];
        ((float*)s_adj)[t] = adj[(size_t)g * (N * N) + t];
    }
    __syncthreads();

    // adj column means: c[m] = (1/16) sum_n adj[n][m]
    if (t < N) {
        float s = 0.f;
        #pragma unroll
        for (int n = 0; n < N; ++n) s += s_adj[n][t];
        s_c[t] = s * 0.0625f;
    }

    // ---- layer 1 GEMM: s_a[n][f] = sum_d s_x[n][d] * W1[d][f]
    // thread -> (f = t&127, half = t>>7 owning 8 nodes). x reads are
    // wave-uniform LDS broadcasts (float4); W1 reads coalesced, L2-resident.
    {
        const int f = t & (D_H - 1);
        const int half = t >> 7;
        float acc[8] = {};
        for (int d = 0; d < D_IN; d += 4) {
            float4 xv[8];
            #pragma unroll
            for (int i = 0; i < 8; ++i)
                xv[i] = *(const float4*)&s_x[half * 8 + i][d];
            #pragma unroll
            for (int k = 0; k < 4; ++k) {
                const float w = W1[(d + k) * D_H + f];
                #pragma unroll
                for (int i = 0; i < 8; ++i)
                    acc[i] = fmaf(reinterpret_cast<const float*>(&xv[i])[k], w, acc[i]);
            }
        }
        #pragma unroll
        for (int i = 0; i < 8; ++i) s_a[half * 8 + i][f] = acc[i];
    }
    __syncthreads();

    // ---- mix1 + relu: s_b_[n][f] = relu(sum_m adj[n][m]*s_a[m][f] + b1[f])
    {
        const int f = t & (D_H - 1);
        const int half = t >> 7;
        const float bias = b1[f];
        #pragma unroll
        for (int i = 0; i < 8; ++i) {
            const int n = half * 8 + i;
            float s = bias;
            #pragma unroll
            for (int m = 0; m < N; ++m) s = fmaf(s_adj[n][m], s_a[m][f], s);
            s_b_[n][f] = fmaxf(s, 0.f);
        }
    }
    __syncthreads();

    // ---- layer 2 GEMM: s_a[n][f2] = sum_d s_b_[n][d] * W2[d][f2]   (f2 < 64)
    {
        const int f2 = t & (D_H2 - 1);
        const int q = t >> 6;  // 0..3 -> nodes q*4 .. q*4+3
        float acc[4] = {};
        for (int d = 0; d < D_H; ++d) {
            const float w = W2[d * D_H2 + f2];
            #pragma unroll
            for (int i = 0; i < 4; ++i)
                acc[i] = fmaf(s_b_[q * 4 + i][d], w, acc[i]);
        }
        #pragma unroll
        for (int i = 0; i < 4; ++i) s_a[q * 4 + i][f2] = acc[i];
    }
    __syncthreads();

    // ---- mix2 + relu: s_b_[n][f2] = relu(sum_m adj[n][m]*s_a[m][f2] + b2[f2])
    {
        const int f2 = t & (D_H2 - 1);
        const int q = t >> 6;
        const float bias = b2[f2];
        #pragma unroll
        for (int i = 0; i < 4; ++i) {
            const int n = q * 4 + i;
            float s = bias;
            #pragma unroll
            for (int m = 0; m < N; ++m) s = fmaf(s_adj[n][m], s_a[m][f2], s);
            s_b_[n][f2] = fmaxf(s, 0.f);
        }
    }
    __syncthreads();

    // ---- layer 3 GEMM: s_a[n][f3] = sum_d s_b_[n][d] * W3[d][f3]  (f3<32, d<64)
    {
        const int f3 = t & (D_OUT - 1);
        const int o = t >> 5;  // 0..7 -> nodes o*2, o*2+1
        float acc[2] = {};
        for (int d = 0; d < D_H2; ++d) {
            const float w = W3[d * D_OUT + f3];
            #pragma unroll
            for (int i = 0; i < 2; ++i)
                acc[i] = fmaf(s_b_[o * 2 + i][d], w, acc[i]);
        }
        #pragma unroll
        for (int i = 0; i < 2; ++i) s_a[o * 2 + i][f3] = acc[i];
    }
    __syncthreads();

    // ---- final: out[g*32+f] = sum_m c[m]*s3[m][f] + b3[f]
    if (t < D_OUT) {
        float s = b3[t];
        #pragma unroll
        for (int m = 0; m < N; ++m) s = fmaf(s_c[m], s_a[m][t], s);
        out[(size_t)g * D_OUT + t] = s;
    }
}

extern "C" void kernel_launch(void* const* d_in, const int* in_sizes, int n_in,
                              void* d_out, int out_size, void* d_ws, size_t ws_size,
                              hipStream_t stream) {
    const float* x   = (const float*)d_in[0];
    const float* adj = (const float*)d_in[1];
    const float* W1  = (const float*)d_in[2];
    const float* b1  = (const float*)d_in[3];
    const float* W2  = (const float*)d_in[4];
    const float* b2  = (const float*)d_in[5];
    const float* W3  = (const float*)d_in[6];
    const float* b3  = (const float*)d_in[7];
    gcn_fused<<<16384, 256, 0, stream>>>(x, adj, W1, b1, W2, b2, W3, b3, (float*)d_out);
}

// Round 2
// 393.645 us; speedup vs baseline: 1.9161x; 1.9161x over previous
//
#include <hip/hip_runtime.h>

// GCN fused, fp16 MFMA. B=16384 graphs, N=16 nodes, 256->128->64->32, node-mean.
// One wave = one graph (wave-synchronous, no __syncthreads). 4 graphs/block.
// Weights pre-packed into 16x16x32 B-fragment order by pack_weights prologue.
// Chain trick: 16x16x32 C-layout (row=q*4+reg,col=lane&15) == 16x16x16 B-layout
// (k=q*4+j,n=lane&15), so adj-mix MFMAs consume GEMM accumulators in-register.
// LDS 52.1 KB/block -> 3 blocks/CU.

typedef _Float16 half4_t __attribute__((ext_vector_type(4)));
typedef _Float16 half8_t __attribute__((ext_vector_type(8)));
typedef float    float4_t __attribute__((ext_vector_type(4)));

// ---------------- prologue: pack W1,W2,W3 (fp32 [K][N]) into fp16 B-frags ----
// frag[(nt*KSTEPS+ks)*64+lane][j] = W[ks*32 + (lane>>4)*8 + j][nt*16 + (lane&15)]
__global__ __launch_bounds__(256) void pack_weights(
    const float* __restrict__ W1, const float* __restrict__ W2,
    const float* __restrict__ W3, _Float16* __restrict__ wf)
{
    const int idx = blockIdx.x * 256 + threadIdx.x;
    if (idx < 4096) {                 // W1: 8 N-tiles x 8 K-steps
        const int lane = idx & 63, ks = (idx >> 6) & 7, nt = idx >> 9;
        const int k0 = ks * 32 + ((lane >> 4) << 3), n = nt * 16 + (lane & 15);
        half8_t h;
        #pragma unroll
        for (int j = 0; j < 8; ++j) h[j] = (_Float16)W1[(k0 + j) * 128 + n];
        *(half8_t*)(wf + (size_t)idx * 8) = h;
    } else if (idx < 5120) {          // W2: 4 x 4
        const int i = idx - 4096;
        const int lane = i & 63, ks = (i >> 6) & 3, nt = i >> 8;
        const int k0 = ks * 32 + ((lane >> 4) << 3), n = nt * 16 + (lane & 15);
        half8_t h;
        #pragma unroll
        for (int j = 0; j < 8; ++j) h[j] = (_Float16)W2[(k0 + j) * 64 + n];
        *(half8_t*)(wf + 32768 + (size_t)i * 8) = h;
    } else if (idx < 5376) {          // W3: 2 x 2
        const int i = idx - 5120;
        const int lane = i & 63, ks = (i >> 6) & 1, nt = i >> 7;
        const int k0 = ks * 32 + ((lane >> 4) << 3), n = nt * 16 + (lane & 15);
        half8_t h;
        #pragma unroll
        for (int j = 0; j < 8; ++j) h[j] = (_Float16)W3[(k0 + j) * 32 + n];
        *(half8_t*)(wf + 40960 + (size_t)i * 8) = h;
    }
}

// ---------------- main kernel ----------------
__global__ __launch_bounds__(256) void gcn_mfma(
    const float* __restrict__ x,    // [B,16,256]
    const float* __restrict__ adj,  // [B,16,16]
    const float* __restrict__ b1, const float* __restrict__ b2,
    const float* __restrict__ b3,
    const _Float16* __restrict__ wf,
    float* __restrict__ out)        // [B,32]
{
    constexpr int XW = 264;   // x row stride (halves): 256+8 pad -> 2-way banks
    constexpr int A1W = 136;  // act1 stride: 128+8
    constexpr int A2W = 72;   // act2 stride: 64+8
    constexpr int PW = 16 * XW + 16 * A1W + 256 + 16;  // per-wave halves = 6672
    __shared__ _Float16 smem[4 * PW];                  // 53376 B

    const int t = threadIdx.x;
    const int lane = t & 63;
    const int w = t >> 6;
    const int g = blockIdx.x * 4 + w;
    const int q = lane >> 4, n16 = lane & 15;

    _Float16* sx   = smem + w * PW;
    _Float16* sa1  = sx + 16 * XW;
    _Float16* sadj = sa1 + 16 * A1W;
    _Float16* sc   = sadj + 256;
    _Float16* sa2  = sx;            // alias: x dead after layer-1 k-loop

    // ---- stage x -> fp16 LDS (row i, lane covers 4 consecutive cols)
    {
        const float* xg = x + (size_t)g * 4096;
        #pragma unroll
        for (int i = 0; i < 16; ++i) {
            float4_t v = *(const float4_t*)(xg + i * 256 + lane * 4);
            half4_t h;
            h[0] = (_Float16)v[0]; h[1] = (_Float16)v[1];
            h[2] = (_Float16)v[2]; h[3] = (_Float16)v[3];
            *(half4_t*)(sx + i * XW + lane * 4) = h;
        }
    }
    // ---- stage adj (fp16) + column means c[m] = mean_n adj[n][m]
    {
        const float* ag = adj + (size_t)g * 256;
        float4_t v = *(const float4_t*)(ag + lane * 4);  // n=lane>>2, m=(lane&3)*4..+3
        half4_t h;
        h[0] = (_Float16)v[0]; h[1] = (_Float16)v[1];
        h[2] = (_Float16)v[2]; h[3] = (_Float16)v[3];
        *(half4_t*)(sadj + (lane >> 2) * 16 + (lane & 3) * 4) = h;
        float4_t s = v;
        #pragma unroll
        for (int d = 4; d < 64; d <<= 1) {
            s[0] += __shfl_xor(s[0], d);
            s[1] += __shfl_xor(s[1], d);
            s[2] += __shfl_xor(s[2], d);
            s[3] += __shfl_xor(s[3], d);
        }
        if (lane < 4) {
            half4_t hc;
            hc[0] = (_Float16)(s[0] * 0.0625f); hc[1] = (_Float16)(s[1] * 0.0625f);
            hc[2] = (_Float16)(s[2] * 0.0625f); hc[3] = (_Float16)(s[3] * 0.0625f);
            *(half4_t*)(sc + lane * 4) = hc;
        }
    }

    const half4_t adjA = *(const half4_t*)(sadj + n16 * 16 + q * 4);
    const float4_t zero = {0.f, 0.f, 0.f, 0.f};

    // ---- layer 1: support1 = x @ W1   (8 N-tiles, 8 K-steps)
    float4_t acc1[8];
    #pragma unroll
    for (int nt = 0; nt < 8; ++nt) acc1[nt] = zero;
    for (int ks = 0; ks < 8; ++ks) {
        half8_t a = *(const half8_t*)(sx + n16 * XW + ks * 32 + q * 8);
        #pragma unroll
        for (int nt = 0; nt < 8; ++nt) {
            half8_t b = *(const half8_t*)(wf + ((size_t)(nt * 8 + ks) * 64 + lane) * 8);
            acc1[nt] = __builtin_amdgcn_mfma_f32_16x16x32_f16(a, b, acc1[nt], 0, 0, 0);
        }
    }
    // ---- mix1 (adj @ support1) + bias + relu -> sa1
    #pragma unroll
    for (int nt = 0; nt < 8; ++nt) {
        half4_t p;
        p[0] = (_Float16)acc1[nt][0]; p[1] = (_Float16)acc1[nt][1];
        p[2] = (_Float16)acc1[nt][2]; p[3] = (_Float16)acc1[nt][3];
        float4_t m = __builtin_amdgcn_mfma_f32_16x16x16f16(adjA, p, zero, 0, 0, 0);
        const float bias = b1[nt * 16 + n16];
        #pragma unroll
        for (int r = 0; r < 4; ++r)
            sa1[(q * 4 + r) * A1W + nt * 16 + n16] = (_Float16)fmaxf(m[r] + bias, 0.f);
    }

    // ---- layer 2: support2 = act1 @ W2   (4 N-tiles, 4 K-steps)
    float4_t acc2[4];
    #pragma unroll
    for (int nt = 0; nt < 4; ++nt) acc2[nt] = zero;
    for (int ks = 0; ks < 4; ++ks) {
        half8_t a = *(const half8_t*)(sa1 + n16 * A1W + ks * 32 + q * 8);
        #pragma unroll
        for (int nt = 0; nt < 4; ++nt) {
            half8_t b = *(const half8_t*)(wf + 32768 + ((size_t)(nt * 4 + ks) * 64 + lane) * 8);
            acc2[nt] = __builtin_amdgcn_mfma_f32_16x16x32_f16(a, b, acc2[nt], 0, 0, 0);
        }
    }
    // ---- mix2 + bias + relu -> sa2
    #pragma unroll
    for (int nt = 0; nt < 4; ++nt) {
        half4_t p;
        p[0] = (_Float16)acc2[nt][0]; p[1] = (_Float16)acc2[nt][1];
        p[2] = (_Float16)acc2[nt][2]; p[3] = (_Float16)acc2[nt][3];
        float4_t m = __builtin_amdgcn_mfma_f32_16x16x16f16(adjA, p, zero, 0, 0, 0);
        const float bias = b2[nt * 16 + n16];
        #pragma unroll
        for (int r = 0; r < 4; ++r)
            sa2[(q * 4 + r) * A2W + nt * 16 + n16] = (_Float16)fmaxf(m[r] + bias, 0.f);
    }

    // ---- layer 3: support3 = act2 @ W3   (2 N-tiles, 2 K-steps)
    float4_t acc3[2];
    acc3[0] = zero; acc3[1] = zero;
    for (int ks = 0; ks < 2; ++ks) {
        half8_t a = *(const half8_t*)(sa2 + n16 * A2W + ks * 32 + q * 8);
        #pragma unroll
        for (int nt = 0; nt < 2; ++nt) {
            half8_t b = *(const half8_t*)(wf + 40960 + ((size_t)(nt * 2 + ks) * 64 + lane) * 8);
            acc3[nt] = __builtin_amdgcn_mfma_f32_16x16x32_f16(a, b, acc3[nt], 0, 0, 0);
        }
    }
    // ---- final: out[f] = colmean(adj)^T @ support3 + b3 (all rows identical)
    const half4_t cf = *(const half4_t*)(sc + q * 4);  // A[m][k]=c[k] broadcast
    #pragma unroll
    for (int nt = 0; nt < 2; ++nt) {
        half4_t p;
        p[0] = (_Float16)acc3[nt][0]; p[1] = (_Float16)acc3[nt][1];
        p[2] = (_Float16)acc3[nt][2]; p[3] = (_Float16)acc3[nt][3];
        float4_t o = __builtin_amdgcn_mfma_f32_16x16x16f16(cf, p, zero, 0, 0, 0);
        if (q == 0)
            out[(size_t)g * 32 + nt * 16 + n16] = o[0] + b3[nt * 16 + n16];
    }
}

extern "C" void kernel_launch(void* const* d_in, const int* in_sizes, int n_in,
                              void* d_out, int out_size, void* d_ws, size_t ws_size,
                              hipStream_t stream) {
    const float* x   = (const float*)d_in[0];
    const float* adj = (const float*)d_in[1];
    const float* W1  = (const float*)d_in[2];
    const float* b1  = (const float*)d_in[3];
    const float* W2  = (const float*)d_in[4];
    const float* b2  = (const float*)d_in[5];
    const float* W3  = (const float*)d_in[6];
    const float* b3  = (const float*)d_in[7];
    _Float16* wf = (_Float16*)d_ws;   // 42 KB more than available? uses 84 KB of ws
    pack_weights<<<21, 256, 0, stream>>>(W1, W2, W3, wf);
    gcn_mfma<<<4096, 256, 0, stream>>>(x, adj, b1, b2, b3, wf, (float*)d_out);
}